// Round 8
// baseline (308.102 us; speedup 1.0000x reference)
//
#include <hip/hip_runtime.h>

// FullNN: per-atom MLP (FEAT=64 -> tanh(HID=64) -> 1) + segment-sum over 32768 structs.
// Round 8: ABLATION. Rounds 3-7 all pinned at ~220us/dispatch with nothing saturated
// (VALU 28-41%, MFMA 4.4%, HBM 22-27%) across prefetch/grid/atomic-split/swapped-GEMM
// changes. The never-ablated invariant: 3M scattered device-scope f32 atomics
// (13.6 G/s). Split into two kernels to localize the stall:
//   1) atom_mlp_e: swapped-GEMM MFMA MLP -> DENSE per-atom energy store (no atomics)
//   2) scatter_sum: e + idx -> atomicAdd into d_out (nothing else)
// Per-dispatch rocprof rows give each phase's true cost.
//
// Layouts (learn_hip m89/m97), mfma_f32_16x16x32_bf16, swapped H^T = W1^T @ x^T:
//   A: row = lane&15, k = (lane>>4)*8+i  -> W1^T frag
//   B: col = lane&15, k = (lane>>4)*8+i  -> x^T frag
//   D: col = lane&15 (= atom), row j = 16t + kg*4 + r  -> in-lane W2 reduce, 2 shfls

typedef __attribute__((ext_vector_type(8))) short bf16x8;
typedef __attribute__((ext_vector_type(4))) float f32x4;

struct ElemPtrs {
    const float* x;
    const int*   idx;
    const float* W1;
    const float* b1;
    const float* W2;
    const float* b2;
};
struct Params {
    ElemPtrs e[3];
    int n_tiles;    // atoms / 16
    int n_atoms;
    int n_struct;   // 32768
    int ncopies;    // fused-fallback only
};

__device__ __forceinline__ short f2bf(float f) {
    __bf16 h = (__bf16)f;           // hardware RNE; pairs into v_cvt_pk_bf16_f32
    return __builtin_bit_cast(short, h);
}

__device__ __forceinline__ float fast_tanh(float v) {
    v = __builtin_amdgcn_fmed3f(v, -10.0f, 10.0f);
    float t = __builtin_amdgcn_exp2f(v * 2.8853900817779268f); // 2^(2v*log2 e)
    return (t - 1.0f) * __builtin_amdgcn_rcpf(t + 1.0f);
}

// ---------------- kernel 1: MLP -> dense per-atom energies (no atomics) ----------------
__global__ __launch_bounds__(256, 4) void atom_mlp_e(Params p, float* __restrict__ evec)
{
    const ElemPtrs ep = p.e[blockIdx.y];
    float* __restrict__ eout = evec + (size_t)blockIdx.y * p.n_atoms;

    const int lane = threadIdx.x & 63;
    const int col  = lane & 15;
    const int kg   = lane >> 4;

    const int wid    = (blockIdx.x * 256 + threadIdx.x) >> 6;
    const int nwaves = (gridDim.x * 256) >> 6;

    f32x4 b1c[4], w2c[4];
    #pragma unroll
    for (int t = 0; t < 4; ++t)
        #pragma unroll
        for (int r = 0; r < 4; ++r) {
            b1c[t][r] = ep.b1[16 * t + kg * 4 + r];
            w2c[t][r] = ep.W2[16 * t + kg * 4 + r];
        }
    const float b2v = ep.b2[0];

    bf16x8 Wf[2][4];
    #pragma unroll
    for (int s = 0; s < 2; ++s)
        #pragma unroll
        for (int t = 0; t < 4; ++t)
            #pragma unroll
            for (int i = 0; i < 8; ++i)
                Wf[s][t][i] = f2bf(ep.W1[(s * 32 + kg * 8 + i) * 64 + 16 * t + col]);

    int tile = wid;
    if (tile >= p.n_tiles) return;          // wave-uniform

    const size_t xoff    = (size_t)col * 64 + (size_t)kg * 8;
    const size_t xstride = (size_t)nwaves * 1024;

    const float* xp = ep.x + (size_t)tile * 1024 + xoff;

    // raw-float4 prefetch (convert INSIDE compute, so vmcnt wait lands after MFMA issue)
    float4 c0 = *reinterpret_cast<const float4*>(xp);
    float4 c1 = *reinterpret_cast<const float4*>(xp + 4);
    float4 c2 = *reinterpret_cast<const float4*>(xp + 32);
    float4 c3 = *reinterpret_cast<const float4*>(xp + 36);

    while (true) {
        const int nxt = tile + nwaves;
        const bool have = (nxt < p.n_tiles);   // wave-uniform
        float4 n0, n1, n2, n3;
        if (have) {
            const float* xn = xp + xstride;
            n0 = *reinterpret_cast<const float4*>(xn);
            n1 = *reinterpret_cast<const float4*>(xn + 4);
            n2 = *reinterpret_cast<const float4*>(xn + 32);
            n3 = *reinterpret_cast<const float4*>(xn + 36);
            xp = xn;
        }

        bf16x8 X0, X1;
        X0[0]=f2bf(c0.x); X0[1]=f2bf(c0.y); X0[2]=f2bf(c0.z); X0[3]=f2bf(c0.w);
        X0[4]=f2bf(c1.x); X0[5]=f2bf(c1.y); X0[6]=f2bf(c1.z); X0[7]=f2bf(c1.w);
        X1[0]=f2bf(c2.x); X1[1]=f2bf(c2.y); X1[2]=f2bf(c2.z); X1[3]=f2bf(c2.w);
        X1[4]=f2bf(c3.x); X1[5]=f2bf(c3.y); X1[6]=f2bf(c3.z); X1[7]=f2bf(c3.w);

        f32x4 a0 = __builtin_amdgcn_mfma_f32_16x16x32_bf16(Wf[0][0], X0, b1c[0], 0, 0, 0);
        f32x4 a1 = __builtin_amdgcn_mfma_f32_16x16x32_bf16(Wf[0][1], X0, b1c[1], 0, 0, 0);
        f32x4 a2 = __builtin_amdgcn_mfma_f32_16x16x32_bf16(Wf[0][2], X0, b1c[2], 0, 0, 0);
        f32x4 a3 = __builtin_amdgcn_mfma_f32_16x16x32_bf16(Wf[0][3], X0, b1c[3], 0, 0, 0);
        a0 = __builtin_amdgcn_mfma_f32_16x16x32_bf16(Wf[1][0], X1, a0, 0, 0, 0);
        a1 = __builtin_amdgcn_mfma_f32_16x16x32_bf16(Wf[1][1], X1, a1, 0, 0, 0);
        a2 = __builtin_amdgcn_mfma_f32_16x16x32_bf16(Wf[1][2], X1, a2, 0, 0, 0);
        a3 = __builtin_amdgcn_mfma_f32_16x16x32_bf16(Wf[1][3], X1, a3, 0, 0, 0);

        float ev;
        ev  = fast_tanh(a0[0]) * w2c[0][0];
        ev += fast_tanh(a0[1]) * w2c[0][1];
        ev += fast_tanh(a0[2]) * w2c[0][2];
        ev += fast_tanh(a0[3]) * w2c[0][3];
        ev += fast_tanh(a1[0]) * w2c[1][0];
        ev += fast_tanh(a1[1]) * w2c[1][1];
        ev += fast_tanh(a1[2]) * w2c[1][2];
        ev += fast_tanh(a1[3]) * w2c[1][3];
        ev += fast_tanh(a2[0]) * w2c[2][0];
        ev += fast_tanh(a2[1]) * w2c[2][1];
        ev += fast_tanh(a2[2]) * w2c[2][2];
        ev += fast_tanh(a2[3]) * w2c[2][3];
        ev += fast_tanh(a3[0]) * w2c[3][0];
        ev += fast_tanh(a3[1]) * w2c[3][1];
        ev += fast_tanh(a3[2]) * w2c[3][2];
        ev += fast_tanh(a3[3]) * w2c[3][3];
        ev += __shfl_xor(ev, 16);
        ev += __shfl_xor(ev, 32);

        if (lane < 16) eout[tile * 16 + col] = ev + b2v;   // coalesced 64B store/wave

        if (!have) break;
        c0 = n0; c1 = n1; c2 = n2; c3 = n3;
        tile = nxt;
    }
}

// ---------------- kernel 2: pure scatter (the ablated phase) ----------------
struct IdxPtrs { const int* idx[3]; };

__global__ __launch_bounds__(256) void scatter_sum(IdxPtrs ip, const float* __restrict__ evec,
                                                   int n_atoms, float* __restrict__ out)
{
    const int t = blockIdx.x * 256 + threadIdx.x;
    const int n4 = n_atoms >> 2;
    if (t >= n4) return;
    const int e = blockIdx.y;
    const int4   id = reinterpret_cast<const int4*>(ip.idx[e])[t];
    const float4 ev = reinterpret_cast<const float4*>(evec + (size_t)e * n_atoms)[t];
    atomicAdd(&out[id.x], ev.x);
    atomicAdd(&out[id.y], ev.y);
    atomicAdd(&out[id.z], ev.z);
    atomicAdd(&out[id.w], ev.w);
}

// ---------------- fused fallback (round-7 path) if ws too small ----------------
__global__ __launch_bounds__(256, 4) void atom_mlp_fused(Params p, float* __restrict__ out)
{
    const ElemPtrs ep = p.e[blockIdx.y];

    const int lane = threadIdx.x & 63;
    const int col  = lane & 15;
    const int kg   = lane >> 4;

    const int wid    = (blockIdx.x * 256 + threadIdx.x) >> 6;
    const int nwaves = (gridDim.x * 256) >> 6;

    f32x4 b1c[4], w2c[4];
    #pragma unroll
    for (int t = 0; t < 4; ++t)
        #pragma unroll
        for (int r = 0; r < 4; ++r) {
            b1c[t][r] = ep.b1[16 * t + kg * 4 + r];
            w2c[t][r] = ep.W2[16 * t + kg * 4 + r];
        }
    const float b2v = ep.b2[0];

    bf16x8 Wf[2][4];
    #pragma unroll
    for (int s = 0; s < 2; ++s)
        #pragma unroll
        for (int t = 0; t < 4; ++t)
            #pragma unroll
            for (int i = 0; i < 8; ++i)
                Wf[s][t][i] = f2bf(ep.W1[(s * 32 + kg * 8 + i) * 64 + 16 * t + col]);

    int tile = wid;
    if (tile >= p.n_tiles) return;

    const size_t xoff = (size_t)col * 64 + (size_t)kg * 8;

    for (; tile < p.n_tiles; tile += nwaves) {
        const float* xp = ep.x + (size_t)tile * 1024 + xoff;
        float4 c0 = *reinterpret_cast<const float4*>(xp);
        float4 c1 = *reinterpret_cast<const float4*>(xp + 4);
        float4 c2 = *reinterpret_cast<const float4*>(xp + 32);
        float4 c3 = *reinterpret_cast<const float4*>(xp + 36);
        const int idxv = ep.idx[tile * 16 + col];

        bf16x8 X0, X1;
        X0[0]=f2bf(c0.x); X0[1]=f2bf(c0.y); X0[2]=f2bf(c0.z); X0[3]=f2bf(c0.w);
        X0[4]=f2bf(c1.x); X0[5]=f2bf(c1.y); X0[6]=f2bf(c1.z); X0[7]=f2bf(c1.w);
        X1[0]=f2bf(c2.x); X1[1]=f2bf(c2.y); X1[2]=f2bf(c2.z); X1[3]=f2bf(c2.w);
        X1[4]=f2bf(c3.x); X1[5]=f2bf(c3.y); X1[6]=f2bf(c3.z); X1[7]=f2bf(c3.w);

        f32x4 a0 = __builtin_amdgcn_mfma_f32_16x16x32_bf16(Wf[0][0], X0, b1c[0], 0, 0, 0);
        f32x4 a1 = __builtin_amdgcn_mfma_f32_16x16x32_bf16(Wf[0][1], X0, b1c[1], 0, 0, 0);
        f32x4 a2 = __builtin_amdgcn_mfma_f32_16x16x32_bf16(Wf[0][2], X0, b1c[2], 0, 0, 0);
        f32x4 a3 = __builtin_amdgcn_mfma_f32_16x16x32_bf16(Wf[0][3], X0, b1c[3], 0, 0, 0);
        a0 = __builtin_amdgcn_mfma_f32_16x16x32_bf16(Wf[1][0], X1, a0, 0, 0, 0);
        a1 = __builtin_amdgcn_mfma_f32_16x16x32_bf16(Wf[1][1], X1, a1, 0, 0, 0);
        a2 = __builtin_amdgcn_mfma_f32_16x16x32_bf16(Wf[1][2], X1, a2, 0, 0, 0);
        a3 = __builtin_amdgcn_mfma_f32_16x16x32_bf16(Wf[1][3], X1, a3, 0, 0, 0);

        float ev;
        ev  = fast_tanh(a0[0]) * w2c[0][0];
        ev += fast_tanh(a0[1]) * w2c[0][1];
        ev += fast_tanh(a0[2]) * w2c[0][2];
        ev += fast_tanh(a0[3]) * w2c[0][3];
        ev += fast_tanh(a1[0]) * w2c[1][0];
        ev += fast_tanh(a1[1]) * w2c[1][1];
        ev += fast_tanh(a1[2]) * w2c[1][2];
        ev += fast_tanh(a1[3]) * w2c[1][3];
        ev += fast_tanh(a2[0]) * w2c[2][0];
        ev += fast_tanh(a2[1]) * w2c[2][1];
        ev += fast_tanh(a2[2]) * w2c[2][2];
        ev += fast_tanh(a2[3]) * w2c[2][3];
        ev += fast_tanh(a3[0]) * w2c[3][0];
        ev += fast_tanh(a3[1]) * w2c[3][1];
        ev += fast_tanh(a3[2]) * w2c[3][2];
        ev += fast_tanh(a3[3]) * w2c[3][3];
        ev += __shfl_xor(ev, 16);
        ev += __shfl_xor(ev, 32);

        if (lane < 16) atomicAdd(&out[idxv], ev + b2v);
    }
}

extern "C" void kernel_launch(void* const* d_in, const int* in_sizes, int n_in,
                              void* d_out, int out_size, void* d_ws, size_t ws_size,
                              hipStream_t stream) {
    Params p;
    IdxPtrs ip;
    for (int e = 0; e < 3; ++e) {
        p.e[e].x   = (const float*)d_in[6 * e + 0];
        p.e[e].idx = (const int*)  d_in[6 * e + 1];
        p.e[e].W1  = (const float*)d_in[6 * e + 2];
        p.e[e].b1  = (const float*)d_in[6 * e + 3];
        p.e[e].W2  = (const float*)d_in[6 * e + 4];
        p.e[e].b2  = (const float*)d_in[6 * e + 5];
        ip.idx[e]  = p.e[e].idx;
    }
    p.n_atoms  = in_sizes[0] / 64;
    p.n_tiles  = p.n_atoms / 16;   // 62,500
    p.n_struct = out_size;         // 32768
    p.ncopies  = 1;

    float* out = (float*)d_out;
    hipMemsetAsync(out, 0, (size_t)out_size * sizeof(float), stream);

    const size_t need = (size_t)3 * p.n_atoms * sizeof(float);   // 12 MB
    if (ws_size >= need) {
        float* evec = (float*)d_ws;
        dim3 grid1(683, 3);
        atom_mlp_e<<<grid1, 256, 0, stream>>>(p, evec);
        dim3 grid2((p.n_atoms / 4 + 255) / 256, 3);
        scatter_sum<<<grid2, 256, 0, stream>>>(ip, evec, p.n_atoms, out);
    } else {
        dim3 grid(683, 3);
        atom_mlp_fused<<<grid, 256, 0, stream>>>(p, out);
    }
}

// Round 9
// 212.886 us; speedup vs baseline: 1.4473x; 1.4473x over previous
//
#include <hip/hip_runtime.h>

// FullNN: per-atom MLP (FEAT=64 -> tanh(HID=64) -> 1) + segment-sum over 32768 structs.
// Round 9: round-8 ablation proved atomics innocent -- the MLP kernel alone pins at
// 205us with nothing saturated (latency-bound on the x path; ~4 waves/SIMD because
// VGPR(60)+AGPR(~48) on the unified file, depth-1 prefetch, stride-256B lanes).
// Fix: canonical wave-private LDS staging -- global_load_lds width=16 (contiguous
// 1KB/instr, no VGPR cost), depth-2 double buffer per wave (8KB in flight), counted
// vmcnt (never 0 in steady state), G4 XOR swizzle (chunk ^= row&7) applied on both
// sides (pre-swizzled global source; linear LDS dest -- rule #21). Atomics fused
// back (proven ~15us marginal in-kernel), 8-way split accumulator copies kept.
//
// MFMA mfma_f32_16x16x32_bf16, swapped H^T = W1^T @ x^T (learn_hip m89/m97):
//   A: row=lane&15, k=(lane>>4)*8+i -> W1^T frag (persistent registers)
//   B: col=lane&15 (= atom), k=(lane>>4)*8+i -> x^T frag (from LDS)
//   D: col=lane&15 (= atom), j=16t+kg*4+r    -> in-lane W2 reduce, 2 shfls

typedef __attribute__((ext_vector_type(8))) short bf16x8;
typedef __attribute__((ext_vector_type(4))) float f32x4;

typedef const __attribute__((address_space(1))) void* as1cv;
typedef __attribute__((address_space(3))) void* as3v;

struct ElemPtrs {
    const float* x;
    const int*   idx;
    const float* W1;
    const float* b1;
    const float* W2;
    const float* b2;
};
struct Params {
    ElemPtrs e[3];
    int n_tiles;    // atoms / 16
    int n_struct;   // 32768
    int ncopies;    // split-accumulator count (8, or 1 fallback)
};

__device__ __forceinline__ short f2bf(float f) {
    __bf16 h = (__bf16)f;           // hardware RNE; pairs into v_cvt_pk_bf16_f32
    return __builtin_bit_cast(short, h);
}

__device__ __forceinline__ float fast_tanh(float v) {
    v = __builtin_amdgcn_fmed3f(v, -10.0f, 10.0f);
    float t = __builtin_amdgcn_exp2f(v * 2.8853900817779268f); // 2^(2v*log2 e)
    return (t - 1.0f) * __builtin_amdgcn_rcpf(t + 1.0f);
}

#define VMWAIT(n) asm volatile("s_waitcnt vmcnt(" #n ")" ::: "memory")
#define CBAR()    asm volatile("" ::: "memory")

__global__ __launch_bounds__(256, 4) void atom_mlp_lds(Params p, float* __restrict__ part)
{
    const ElemPtrs ep = p.e[blockIdx.y];   // uniform index -> scalar code

    // per-wave LDS: 2 buffers x 4KB (one 16x64 f32 tile each)
    __shared__ char smem[4][8192];
    const int wv   = threadIdx.x >> 6;
    const int lane = threadIdx.x & 63;
    const int col  = lane & 15;            // atom within tile
    const int kg   = lane >> 4;            // k-group
    char* wbase = &smem[wv][0];

    float* __restrict__ acc_out = part + (size_t)(blockIdx.x & (p.ncopies - 1)) * p.n_struct;

    // per-lane parameters
    f32x4 b1c[4], w2c[4];
    #pragma unroll
    for (int t = 0; t < 4; ++t)
        #pragma unroll
        for (int r = 0; r < 4; ++r) {
            b1c[t][r] = ep.b1[16 * t + kg * 4 + r];
            w2c[t][r] = ep.W2[16 * t + kg * 4 + r];
        }
    const float b2v = ep.b2[0];

    // persistent W1^T A-fragments, 32 VGPR
    bf16x8 Wf[2][4];
    #pragma unroll
    for (int s = 0; s < 2; ++s)
        #pragma unroll
        for (int t = 0; t < 4; ++t)
            #pragma unroll
            for (int i = 0; i < 8; ++i)
                Wf[s][t][i] = f2bf(ep.W1[(s * 32 + kg * 8 + i) * 64 + 16 * t + col]);

    const int wid    = (blockIdx.x * 256 + threadIdx.x) >> 6;
    const int nwaves = (gridDim.x * 256) >> 6;

    // staging source byte-offsets within a tile (pre-swizzled: LDS[r][c] = X[r][c^(r&7)])
    // instr i stages dest chunks t=i*64+lane -> (r,c)=(i*4+kg, col); src chunk = c^(r&7)
    unsigned soff[4];
    #pragma unroll
    for (int i = 0; i < 4; ++i) {
        const unsigned r = i * 4u + (unsigned)kg;
        soff[i] = r * 256u + (((unsigned)col ^ (r & 7u)) << 4);
    }
    // LDS read byte-offsets within a buffer: row=col, chunk e=h*8+kg*2+d, addr chunk = e^(col&7)
    unsigned rdoff[4];
    #pragma unroll
    for (int h = 0; h < 2; ++h)
        #pragma unroll
        for (int d = 0; d < 2; ++d) {
            const unsigned e = (unsigned)(h * 8 + kg * 2 + d);
            rdoff[h * 2 + d] = (unsigned)col * 256u + ((e ^ ((unsigned)col & 7u)) << 4);
        }

    int t0 = wid;
    if (t0 >= p.n_tiles) return;           // wave-uniform
    const char* xb = (const char*)ep.x;
    const int nt = p.n_tiles;

#define STAGE(BUFOFF, TT)                                                          \
    {                                                                              \
        const char* gtb = xb + (size_t)(TT) * 4096;                                \
        __builtin_amdgcn_global_load_lds((as1cv)(gtb + soff[0]),                   \
            (as3v)(wbase + (BUFOFF)),        16, 0, 0);                            \
        __builtin_amdgcn_global_load_lds((as1cv)(gtb + soff[1]),                   \
            (as3v)(wbase + (BUFOFF) + 1024), 16, 0, 0);                            \
        __builtin_amdgcn_global_load_lds((as1cv)(gtb + soff[2]),                   \
            (as3v)(wbase + (BUFOFF) + 2048), 16, 0, 0);                            \
        __builtin_amdgcn_global_load_lds((as1cv)(gtb + soff[3]),                   \
            (as3v)(wbase + (BUFOFF) + 3072), 16, 0, 0);                            \
    }

    // prologue: stage tiles t0 (buf0) and t0+nwaves (buf1); idx rides in each group
    STAGE(0, t0);
    int ia = ep.idx[t0 * 16 + col];
    CBAR();                                 // pin group(t0) | group(t1) segment split
    const int t1 = t0 + nwaves;
    int ib = 0;
    if (t1 < nt) { STAGE(4096, t1); ib = ep.idx[t1 * 16 + col]; }

    unsigned bo = 0;
    int  t = t0;
    bool first = true;

    while (true) {
        const bool havenext = (t + nwaves) < nt;    // group(t+1) staged?
        // wait for group(t): counted vmcnt (segment arithmetic; see round-9 notes)
        if (first) { if (havenext) VMWAIT(5); else VMWAIT(0); }
        else       { if (havenext) VMWAIT(6); else VMWAIT(1); }
        __builtin_amdgcn_sched_barrier(0);

        // LDS -> registers (swizzled, conflict-spread per G4)
        const float4 f0 = *(const float4*)(wbase + bo + rdoff[0]); // k kg*8+0..3
        const float4 f1 = *(const float4*)(wbase + bo + rdoff[1]); // k kg*8+4..7
        const float4 f2 = *(const float4*)(wbase + bo + rdoff[2]); // k 32+kg*8+0..3
        const float4 f3 = *(const float4*)(wbase + bo + rdoff[3]); // k 32+kg*8+4..7

        bf16x8 X0, X1;
        X0[0]=f2bf(f0.x); X0[1]=f2bf(f0.y); X0[2]=f2bf(f0.z); X0[3]=f2bf(f0.w);
        X0[4]=f2bf(f1.x); X0[5]=f2bf(f1.y); X0[6]=f2bf(f1.z); X0[7]=f2bf(f1.w);
        X1[0]=f2bf(f2.x); X1[1]=f2bf(f2.y); X1[2]=f2bf(f2.z); X1[3]=f2bf(f2.w);
        X1[4]=f2bf(f3.x); X1[5]=f2bf(f3.y); X1[6]=f2bf(f3.z); X1[7]=f2bf(f3.w);

        f32x4 a0 = __builtin_amdgcn_mfma_f32_16x16x32_bf16(Wf[0][0], X0, b1c[0], 0, 0, 0);
        f32x4 a1 = __builtin_amdgcn_mfma_f32_16x16x32_bf16(Wf[0][1], X0, b1c[1], 0, 0, 0);
        f32x4 a2 = __builtin_amdgcn_mfma_f32_16x16x32_bf16(Wf[0][2], X0, b1c[2], 0, 0, 0);
        f32x4 a3 = __builtin_amdgcn_mfma_f32_16x16x32_bf16(Wf[0][3], X0, b1c[3], 0, 0, 0);
        a0 = __builtin_amdgcn_mfma_f32_16x16x32_bf16(Wf[1][0], X1, a0, 0, 0, 0);
        a1 = __builtin_amdgcn_mfma_f32_16x16x32_bf16(Wf[1][1], X1, a1, 0, 0, 0);
        a2 = __builtin_amdgcn_mfma_f32_16x16x32_bf16(Wf[1][2], X1, a2, 0, 0, 0);
        a3 = __builtin_amdgcn_mfma_f32_16x16x32_bf16(Wf[1][3], X1, a3, 0, 0, 0);

        float ev;
        ev  = fast_tanh(a0[0]) * w2c[0][0];
        ev += fast_tanh(a0[1]) * w2c[0][1];
        ev += fast_tanh(a0[2]) * w2c[0][2];
        ev += fast_tanh(a0[3]) * w2c[0][3];
        ev += fast_tanh(a1[0]) * w2c[1][0];
        ev += fast_tanh(a1[1]) * w2c[1][1];
        ev += fast_tanh(a1[2]) * w2c[1][2];
        ev += fast_tanh(a1[3]) * w2c[1][3];
        ev += fast_tanh(a2[0]) * w2c[2][0];
        ev += fast_tanh(a2[1]) * w2c[2][1];
        ev += fast_tanh(a2[2]) * w2c[2][2];
        ev += fast_tanh(a2[3]) * w2c[2][3];
        ev += fast_tanh(a3[0]) * w2c[3][0];
        ev += fast_tanh(a3[1]) * w2c[3][1];
        ev += fast_tanh(a3[2]) * w2c[3][2];
        ev += fast_tanh(a3[3]) * w2c[3][3];
        ev += __shfl_xor(ev, 16);
        ev += __shfl_xor(ev, 32);

        if (lane < 16) atomicAdd(&acc_out[ia], ev + b2v);

        if (!havenext) break;
        // rotate: stage tile t+2*nwaves into the buffer just consumed
        const int tn = t + 2 * nwaves;
        ia = ib;
        if (tn < nt) { STAGE(bo, tn); ib = ep.idx[tn * 16 + col]; }
        bo ^= 4096u;
        t += nwaves;
        first = false;
    }
#undef STAGE
}

__global__ __launch_bounds__(256) void reduce_copies(const float* __restrict__ part,
                                                     float* __restrict__ out,
                                                     int n_struct, int ncopies)
{
    const int i = blockIdx.x * 256 + threadIdx.x;
    if (i >= n_struct) return;
    float s = 0.0f;
    for (int c = 0; c < ncopies; ++c)
        s += part[(size_t)c * n_struct + i];
    out[i] = s;
}

extern "C" void kernel_launch(void* const* d_in, const int* in_sizes, int n_in,
                              void* d_out, int out_size, void* d_ws, size_t ws_size,
                              hipStream_t stream) {
    Params p;
    for (int e = 0; e < 3; ++e) {
        p.e[e].x   = (const float*)d_in[6 * e + 0];
        p.e[e].idx = (const int*)  d_in[6 * e + 1];
        p.e[e].W1  = (const float*)d_in[6 * e + 2];
        p.e[e].b1  = (const float*)d_in[6 * e + 3];
        p.e[e].W2  = (const float*)d_in[6 * e + 4];
        p.e[e].b2  = (const float*)d_in[6 * e + 5];
    }
    const int n_atoms = in_sizes[0] / 64;
    p.n_tiles  = n_atoms / 16;   // 62,500
    p.n_struct = out_size;       // 32768

    const size_t need = (size_t)8 * out_size * sizeof(float);   // 1 MB
    float* out = (float*)d_out;

    if (ws_size >= need) {
        p.ncopies = 8;
        float* part = (float*)d_ws;
        hipMemsetAsync(part, 0, need, stream);
        dim3 grid(342, 3);   // ~4 blocks/CU (VGPR+LDS resident set), long per-wave loops
        atom_mlp_lds<<<grid, 256, 0, stream>>>(p, part);
        reduce_copies<<<(out_size + 255) / 256, 256, 0, stream>>>(part, out, out_size, 8);
    } else {
        p.ncopies = 1;
        hipMemsetAsync(out, 0, (size_t)out_size * sizeof(float), stream);
        dim3 grid(342, 3);
        atom_mlp_lds<<<grid, 256, 0, stream>>>(p, out);
    }
}

// Round 10
// 171.820 us; speedup vs baseline: 1.7932x; 1.2390x over previous
//
#include <hip/hip_runtime.h>

// FullNN: per-atom MLP (FEAT=64 -> tanh(HID=64) -> 1) + segment-sum over 32768 structs.
// Round 10: seven structural variants (rounds 3-9) all pinned at 205-240us with no
// pipe saturated and occupancy stuck at ~40%. Per-wave latency hiding is exhausted;
// the lever is CHIP-level concurrency (resident waves x outstanding lines). This
// round shrinks per-wave footprint to raise residency:
//   - W1^T fragments live in LDS (8KB/block, staged once, shared by 4 waves),
//     re-read per tile via inline-asm ds_read_b128 (no LICM hoist back into VGPRs);
//     rule #18: lgkmcnt(0) + sched_barrier(0) before the MFMA cluster.
//   - no software prefetch (proven neutral rounds 4/9) -- TLP does the hiding.
//   - single fused kernel, direct atomics to d_out (round 8: scatter fuses ~free).
//   - grid (1024,3) = 12 blocks/CU so residency is VGPR/LDS-limited, not grid-limited.
//
// MFMA mfma_f32_16x16x32_bf16, swapped H^T = W1^T @ x^T (learn_hip m89/m97):
//   A: row=lane&15, k=(lane>>4)*8+i -> W1^T frag (from LDS)
//   B: col=lane&15 (= atom), k=(lane>>4)*8+i -> x^T frag (registers)
//   D: col=lane&15 (= atom), j=16t+kg*4+r    -> in-lane W2 reduce, 2 shfls

typedef __attribute__((ext_vector_type(8))) short bf16x8;
typedef __attribute__((ext_vector_type(4))) float f32x4;

struct ElemPtrs {
    const float* x;
    const int*   idx;
    const float* W1;
    const float* b1;
    const float* W2;
    const float* b2;
};
struct Params {
    ElemPtrs e[3];
    int n_tiles;   // atoms / 16
};

__device__ __forceinline__ short f2bf(float f) {
    __bf16 h = (__bf16)f;           // hardware RNE; pairs into v_cvt_pk_bf16_f32
    return __builtin_bit_cast(short, h);
}

__device__ __forceinline__ float fast_tanh(float v) {
    v = __builtin_amdgcn_fmed3f(v, -10.0f, 10.0f);
    float t = __builtin_amdgcn_exp2f(v * 2.8853900817779268f); // 2^(2v*log2 e)
    return (t - 1.0f) * __builtin_amdgcn_rcpf(t + 1.0f);
}

__global__ __launch_bounds__(256, 4) void atom_mlp(Params p, float* __restrict__ out)
{
    const ElemPtrs ep = p.e[blockIdx.y];   // uniform index -> scalar code

    // W1^T fragments, shared by the block's 4 waves: [frag fid=s*4+t][lane] x 16B
    __shared__ bf16x8 Wlds[8][64];

    const int tid  = threadIdx.x;
    const int lane = tid & 63;
    const int col  = lane & 15;    // atom within tile
    const int kg   = lane >> 4;    // k-group

    // ---- cooperative stage of W1^T fragments (each thread: 2 frags for its lane) ----
    {
        const int wv = tid >> 6;
        #pragma unroll
        for (int q = 0; q < 2; ++q) {
            const int fid = wv * 2 + q;
            const int s = fid >> 2, t = fid & 3;
            bf16x8 w;
            #pragma unroll
            for (int i = 0; i < 8; ++i)
                w[i] = f2bf(ep.W1[(s * 32 + kg * 8 + i) * 64 + 16 * t + col]);
            Wlds[fid][lane] = w;
        }
    }

    // per-lane b1 (MFMA C-init) and W2, j = 16t + kg*4 + r
    f32x4 b1c[4], w2c[4];
    #pragma unroll
    for (int t = 0; t < 4; ++t)
        #pragma unroll
        for (int r = 0; r < 4; ++r) {
            b1c[t][r] = ep.b1[16 * t + kg * 4 + r];
            w2c[t][r] = ep.W2[16 * t + kg * 4 + r];
        }
    const float b2v = ep.b2[0];

    __syncthreads();

    // 32-bit LDS byte offset of this lane's frag 0 (frag fid at +fid*1024)
    typedef __attribute__((address_space(3))) const void* as3cv;
    const unsigned waddr = (unsigned)(size_t)(as3cv)&Wlds[0][lane];

    const int wid    = (blockIdx.x * 256 + tid) >> 6;
    const int nwaves = (gridDim.x * 256) >> 6;
    const size_t xoff = (size_t)col * 64 + (size_t)kg * 8;

    for (int tile = wid; tile < p.n_tiles; tile += nwaves) {
        const float* xp = ep.x + (size_t)tile * 1024 + xoff;
        const float4 c0 = *reinterpret_cast<const float4*>(xp);
        const float4 c1 = *reinterpret_cast<const float4*>(xp + 4);
        const float4 c2 = *reinterpret_cast<const float4*>(xp + 32);
        const float4 c3 = *reinterpret_cast<const float4*>(xp + 36);
        const int ia = ep.idx[tile * 16 + col];

        bf16x8 X0, X1;
        X0[0]=f2bf(c0.x); X0[1]=f2bf(c0.y); X0[2]=f2bf(c0.z); X0[3]=f2bf(c0.w);
        X0[4]=f2bf(c1.x); X0[5]=f2bf(c1.y); X0[6]=f2bf(c1.z); X0[7]=f2bf(c1.w);
        X1[0]=f2bf(c2.x); X1[1]=f2bf(c2.y); X1[2]=f2bf(c2.z); X1[3]=f2bf(c2.w);
        X1[4]=f2bf(c3.x); X1[5]=f2bf(c3.y); X1[6]=f2bf(c3.z); X1[7]=f2bf(c3.w);

        // ---- frag group 0 (fids 0..3) from LDS, then 4 MFMAs on X0 ----
        bf16x8 w0, w1, w2, w3;
        asm volatile("ds_read_b128 %0, %1 offset:0"    : "=v"(w0) : "v"(waddr));
        asm volatile("ds_read_b128 %0, %1 offset:1024" : "=v"(w1) : "v"(waddr));
        asm volatile("ds_read_b128 %0, %1 offset:2048" : "=v"(w2) : "v"(waddr));
        asm volatile("ds_read_b128 %0, %1 offset:3072" : "=v"(w3) : "v"(waddr));
        asm volatile("s_waitcnt lgkmcnt(0)" ::: "memory");
        __builtin_amdgcn_sched_barrier(0);

        f32x4 a0 = __builtin_amdgcn_mfma_f32_16x16x32_bf16(w0, X0, b1c[0], 0, 0, 0);
        f32x4 a1 = __builtin_amdgcn_mfma_f32_16x16x32_bf16(w1, X0, b1c[1], 0, 0, 0);
        f32x4 a2 = __builtin_amdgcn_mfma_f32_16x16x32_bf16(w2, X0, b1c[2], 0, 0, 0);
        f32x4 a3 = __builtin_amdgcn_mfma_f32_16x16x32_bf16(w3, X0, b1c[3], 0, 0, 0);

        // ---- frag group 1 (fids 4..7) from LDS, then 4 MFMAs on X1 ----
        asm volatile("ds_read_b128 %0, %1 offset:4096" : "=v"(w0) : "v"(waddr));
        asm volatile("ds_read_b128 %0, %1 offset:5120" : "=v"(w1) : "v"(waddr));
        asm volatile("ds_read_b128 %0, %1 offset:6144" : "=v"(w2) : "v"(waddr));
        asm volatile("ds_read_b128 %0, %1 offset:7168" : "=v"(w3) : "v"(waddr));
        asm volatile("s_waitcnt lgkmcnt(0)" ::: "memory");
        __builtin_amdgcn_sched_barrier(0);

        a0 = __builtin_amdgcn_mfma_f32_16x16x32_bf16(w0, X1, a0, 0, 0, 0);
        a1 = __builtin_amdgcn_mfma_f32_16x16x32_bf16(w1, X1, a1, 0, 0, 0);
        a2 = __builtin_amdgcn_mfma_f32_16x16x32_bf16(w2, X1, a2, 0, 0, 0);
        a3 = __builtin_amdgcn_mfma_f32_16x16x32_bf16(w3, X1, a3, 0, 0, 0);

        // epilogue: e = sum_j tanh(H[atom][j]) * W2[j], fully in-lane
        float ev;
        ev  = fast_tanh(a0[0]) * w2c[0][0];
        ev += fast_tanh(a0[1]) * w2c[0][1];
        ev += fast_tanh(a0[2]) * w2c[0][2];
        ev += fast_tanh(a0[3]) * w2c[0][3];
        ev += fast_tanh(a1[0]) * w2c[1][0];
        ev += fast_tanh(a1[1]) * w2c[1][1];
        ev += fast_tanh(a1[2]) * w2c[1][2];
        ev += fast_tanh(a1[3]) * w2c[1][3];
        ev += fast_tanh(a2[0]) * w2c[2][0];
        ev += fast_tanh(a2[1]) * w2c[2][1];
        ev += fast_tanh(a2[2]) * w2c[2][2];
        ev += fast_tanh(a2[3]) * w2c[2][3];
        ev += fast_tanh(a3[0]) * w2c[3][0];
        ev += fast_tanh(a3[1]) * w2c[3][1];
        ev += fast_tanh(a3[2]) * w2c[3][2];
        ev += fast_tanh(a3[3]) * w2c[3][3];
        ev += __shfl_xor(ev, 16);
        ev += __shfl_xor(ev, 32);

        if (lane < 16) atomicAdd(&out[ia], ev + b2v);
    }
}

extern "C" void kernel_launch(void* const* d_in, const int* in_sizes, int n_in,
                              void* d_out, int out_size, void* d_ws, size_t ws_size,
                              hipStream_t stream) {
    Params p;
    for (int e = 0; e < 3; ++e) {
        p.e[e].x   = (const float*)d_in[6 * e + 0];
        p.e[e].idx = (const int*)  d_in[6 * e + 1];
        p.e[e].W1  = (const float*)d_in[6 * e + 2];
        p.e[e].b1  = (const float*)d_in[6 * e + 3];
        p.e[e].W2  = (const float*)d_in[6 * e + 4];
        p.e[e].b2  = (const float*)d_in[6 * e + 5];
    }
    const int n_atoms = in_sizes[0] / 64;
    p.n_tiles = n_atoms / 16;   // 62,500

    float* out = (float*)d_out;
    // d_out is poisoned (0xAA) before timing and NOT re-zeroed between replays.
    hipMemsetAsync(out, 0, (size_t)out_size * sizeof(float), stream);

    // 1024x3 blocks = 12 blocks/CU of grid; residency limited by VGPR/LDS only.
    dim3 grid(1024, 3);
    atom_mlp<<<grid, 256, 0, stream>>>(p, out);
}